// Round 6
// baseline (219.523 us; speedup 1.0000x reference)
//
#include <hip/hip_runtime.h>
#include <hip/hip_bf16.h>

// Disable FP contraction so every multiply/add rounds exactly like the
// numpy/JAX f32 reference (FMA fusion would change discrete voxel coords
// and flip ray_valid bits, which must be exact).
#pragma clang fp contract(off)

#define NRAYS 16384
#define NSAMP 512

typedef __attribute__((ext_vector_type(4))) float floatx4;

static __device__ __forceinline__ unsigned int expand_bits(unsigned int v) {
    v = (v * 65537u) & 4278190335u;
    v = (v * 257u)   & 251719695u;
    v = (v * 17u)    & 3272356035u;
    v = (v * 5u)     & 1227133513u;
    return v;
}

__global__ __launch_bounds__(256) void ca_kernel(
    const float* __restrict__ rays_chunk,
    const float* __restrict__ jitter,
    const int*   __restrict__ bitfield,
    float* __restrict__ out)
{
#pragma clang fp contract(off)
    const int tid  = blockIdx.x * 256 + threadIdx.x;
    const int ray  = tid >> 6;         // one wave per ray
    const int lane = tid & 63;         // samples s = k*256 + lane*4 + i

    // Constants: computed in f64 exactly like Python, then cast to f32.
    const float STEP  = (float)((6.0 - 0.2) / 512.0);
    const float HALFS = (float)(((6.0 - 0.2) / 512.0) / 2.0);
    const float C415  = (float)(4.0 / 15.0);
    const float C512  = (float)(5.0 / 12.0);
    const double br   = 0.0008 * 2.0 / __builtin_sqrt(12.0);
    const float BR2   = (float)(br * br);
    const float DIVB  = 1.984375f;     // BOUND - half_grid, exact in f32

    // Wave-uniform ray params.
    const float* rp = rays_chunk + ray * 6;
    const float ox = rp[0], oy = rp[1], oz = rp[2];
    const float dx = rp[3], dy = rp[4], dz = rp[5];

    // Per-ray null_diag (matches: d_sq, d_mag_sq = max((x+y)+z, 1e-10))
    const float dsx = dx * dx, dsy = dy * dy, dsz = dz * dz;
    float dms = (dsx + dsy) + dsz;
    dms = fmaxf(dms, 1e-10f);
    const float nlx = 1.0f - dsx / dms;
    const float nly = 1.0f - dsy / dms;
    const float nlz = 1.0f - dsz / dms;

    const int sbase = ray * NSAMP;

    // Jitter: two dwordx4 loads, 1KB dense per wave instruction.
    floatx4 jk[2];
    jk[0] = *reinterpret_cast<const floatx4*>(jitter + sbase + (lane << 2));
    jk[1] = *reinterpret_cast<const floatx4*>(jitter + sbase + 256 + (lane << 2));

    const size_t OFF_VALID = (size_t)NRAYS * NSAMP * 4;             // 33554432
    const size_t OFF_Z     = OFF_VALID + (size_t)NRAYS * NSAMP;     // 41943040
    const size_t OFF_D     = OFF_Z     + (size_t)NRAYS * NSAMP;     // 50331648

#pragma unroll
    for (int k = 0; k < 2; ++k) {
        const int s0   = (k << 8) + (lane << 2);   // base sample of this group
        const int idx0 = sbase + s0;
        const floatx4 jv = jk[k];

        // All four z first (needed for in-register dists).
        float zv[4];
#pragma unroll
        for (int i = 0; i < 4; ++i)
            zv[i] = 0.2f + STEP * ((float)(s0 + i) + jv[i]);

        // z[s+4k-group boundary]: next lane's z0 (exact bits). Lane 63 of
        // k=0 recomputes z[256] from lane 0's jk[1].x with the identical
        // expression (bit-identical). k=1 lane 63 is s=511 -> dist=0 below.
        float zn3 = __shfl_down(zv[0], 1);
        if (lane == 63 && k == 0) {
            const float jn = __shfl(jk[1][0], 0);
            zn3 = 0.2f + STEP * (256.0f + jn);
        }

        floatx4 wv, wz, wd;
#pragma unroll
        for (int i = 0; i < 4; ++i) {
            const float z  = zv[i];
            const float t0 = z - HALFS;
            const float t1 = t0 + HALFS;
            const float mu = (t0 + t1) * 0.5f;   // bit-identical to /2
            const float hw = (t1 - t0) * 0.5f;   // bit-identical to /2
            const float mu2 = mu * mu;
            const float hw2 = hw * hw;
            const float hw4 = hw2 * hw2;
            const float denom  = 3.0f * mu2 + hw2;
            const float t_mean = mu + ((2.0f * mu) * hw2) / denom;
            const float inner  = 12.0f * mu2 - hw2;
            const float denom2 = denom * denom;
            const float t_var  = hw2 / 3.0f - (C415 * (hw4 * inner)) / denom2;
            const float r_var  = BR2 * ((mu2 * 0.25f + C512 * hw2) - (C415 * hw4) / denom);

            const float px = ox + dx * t_mean;
            const float py = oy + dy * t_mean;
            const float pz = oz + dz * t_mean;

            const bool outb = (fabsf(px) > 2.0f) | (fabsf(py) > 2.0f) | (fabsf(pz) > 2.0f);

            const float vx = t_var * dsx + r_var * nlx;
            const float vy = t_var * dsy + r_var * nly;
            const float vz = t_var * dsz + r_var * nlz;
            const float vmax = fmaxf(fmaxf(vx, vy), vz);

            // voxel coords — exact reference op order (/2 -> *0.5 bit-identical)
            const float cxn = fminf(fmaxf(px / DIVB, -1.0f), 1.0f);
            const float cyn = fminf(fmaxf(py / DIVB, -1.0f), 1.0f);
            const float czn = fminf(fmaxf(pz / DIVB, -1.0f), 1.0f);
            const float cfx = fminf(fmaxf((cxn + 1.0f) * 0.5f * 127.0f, 0.0f), 127.0f);
            const float cfy = fminf(fmaxf((cyn + 1.0f) * 0.5f * 127.0f, 0.0f), 127.0f);
            const float cfz = fminf(fmaxf((czn + 1.0f) * 0.5f * 127.0f, 0.0f), 127.0f);
            const unsigned int ux = (unsigned int)cfx;
            const unsigned int uy = (unsigned int)cfy;
            const unsigned int uz = (unsigned int)cfz;
            unsigned int m = expand_bits(ux) | (expand_bits(uy) << 1) | (expand_bits(uz) << 2);
            if (m > 2097151u) m = 2097151u;
            const int byte = bitfield[m >> 3];          // random gather, L2-resident
            const bool alpha = ((byte >> (int)(m & 7u)) & 1) != 0;
            const bool valid = (!outb) && alpha;

            const float zn   = (i < 3) ? zv[i + 1] : zn3;
            const float dist = (s0 + i < NSAMP - 1) ? (zn - z) : 0.0f;

            floatx4 xw;
            xw[0] = px; xw[1] = py; xw[2] = pz; xw[3] = vmax;
            __builtin_nontemporal_store(xw,
                reinterpret_cast<floatx4*>(out + (size_t)(idx0 + i) * 4));

            wv[i] = valid ? 1.0f : 0.0f;
            wz[i] = z;
            wd[i] = dist;
        }

        // One dwordx4 per region per k: 1KB dense per wave instruction.
        __builtin_nontemporal_store(wv, reinterpret_cast<floatx4*>(out + OFF_VALID + idx0));
        __builtin_nontemporal_store(wz, reinterpret_cast<floatx4*>(out + OFF_Z     + idx0));
        __builtin_nontemporal_store(wd, reinterpret_cast<floatx4*>(out + OFF_D     + idx0));
    }
}

extern "C" void kernel_launch(void* const* d_in, const int* in_sizes, int n_in,
                              void* d_out, int out_size, void* d_ws, size_t ws_size,
                              hipStream_t stream) {
    const float* rays = (const float*)d_in[0];
    const float* jit  = (const float*)d_in[1];
    const int*   bf   = (const int*)d_in[2];
    float* out = (float*)d_out;

    const int total_threads = NRAYS * NSAMP / 8;   // 1,048,576
    dim3 grid(total_threads / 256), block(256);
    hipLaunchKernelGGL(ca_kernel, grid, block, 0, stream, rays, jit, bf, out);
}

// Round 7
// 57.020 us; speedup vs baseline: 3.8499x; 3.8499x over previous
//
#include <hip/hip_runtime.h>
#include <hip/hip_bf16.h>

// Disable FP contraction so every multiply/add rounds exactly like the
// numpy/JAX f32 reference (FMA fusion would change discrete voxel coords
// and flip ray_valid bits, which must be exact).
#pragma clang fp contract(off)

#define NRAYS 16384
#define NSAMP 512

typedef __attribute__((ext_vector_type(4))) float floatx4;

static __device__ __forceinline__ unsigned int expand_bits(unsigned int v) {
    v = (v * 65537u) & 4278190335u;
    v = (v * 257u)   & 251719695u;
    v = (v * 17u)    & 3272356035u;
    v = (v * 5u)     & 1227133513u;
    return v;
}

__global__ __launch_bounds__(256) void ca_kernel(
    const float* __restrict__ rays_chunk,
    const float* __restrict__ jitter,
    const int*   __restrict__ bitfield,
    float* __restrict__ out)
{
#pragma clang fp contract(off)
    const int tid  = blockIdx.x * 256 + threadIdx.x;
    const int ray  = tid >> 6;         // one wave per ray
    const int lane = tid & 63;         // samples s = lane + 64*k, k=0..7

    // Constants: computed in f64 exactly like Python, then cast to f32.
    const float STEP  = (float)((6.0 - 0.2) / 512.0);
    const float HALFS = (float)(((6.0 - 0.2) / 512.0) / 2.0);
    const float C415  = (float)(4.0 / 15.0);
    const float C512  = (float)(5.0 / 12.0);
    const double br   = 0.0008 * 2.0 / __builtin_sqrt(12.0);
    const float BR2   = (float)(br * br);
    const float DIVB  = 1.984375f;     // BOUND - half_grid, exact in f32

    // Wave-uniform ray params.
    const float* rp = rays_chunk + ray * 6;
    const float ox = rp[0], oy = rp[1], oz = rp[2];
    const float dx = rp[3], dy = rp[4], dz = rp[5];

    // Per-ray null_diag (matches: d_sq, d_mag_sq = max((x+y)+z, 1e-10))
    const float dsx = dx * dx, dsy = dy * dy, dsz = dz * dz;
    float dms = (dsx + dsy) + dsz;
    dms = fmaxf(dms, 1e-10f);
    const float nlx = 1.0f - dsx / dms;
    const float nly = 1.0f - dsy / dms;
    const float nlz = 1.0f - dsz / dms;

    const int sbase = ray * NSAMP;

    // Coalesced jitter loads (256B dense per wave instruction).
    float jloc[8];
#pragma unroll
    for (int k = 0; k < 8; ++k)
        jloc[k] = jitter[sbase + lane + (k << 6)];

    const size_t OFF_VALID = (size_t)NRAYS * NSAMP * 4;             // 33554432
    const size_t OFF_Z     = OFF_VALID + (size_t)NRAYS * NSAMP;     // 41943040
    const size_t OFF_D     = OFF_Z     + (size_t)NRAYS * NSAMP;     // 50331648

#pragma unroll
    for (int k = 0; k < 8; ++k) {
        const int s   = lane + (k << 6);
        const int idx = sbase + s;

        const float z  = 0.2f + STEP * ((float)s + jloc[k]);
        const float t0 = z - HALFS;
        const float t1 = t0 + HALFS;
        const float mu = (t0 + t1) * 0.5f;   // bit-identical to /2
        const float hw = (t1 - t0) * 0.5f;   // bit-identical to /2
        const float mu2 = mu * mu;
        const float hw2 = hw * hw;
        const float hw4 = hw2 * hw2;
        const float denom  = 3.0f * mu2 + hw2;
        const float t_mean = mu + ((2.0f * mu) * hw2) / denom;
        const float inner  = 12.0f * mu2 - hw2;
        const float denom2 = denom * denom;
        const float t_var  = hw2 / 3.0f - (C415 * (hw4 * inner)) / denom2;
        const float r_var  = BR2 * ((mu2 * 0.25f + C512 * hw2) - (C415 * hw4) / denom);

        const float px = ox + dx * t_mean;
        const float py = oy + dy * t_mean;
        const float pz = oz + dz * t_mean;

        // |p|>2 == (p<-2)|(p>2) for finite p; abs is a free operand modifier
        const bool outb = (fabsf(px) > 2.0f) | (fabsf(py) > 2.0f) | (fabsf(pz) > 2.0f);

        const float vx = t_var * dsx + r_var * nlx;
        const float vy = t_var * dsy + r_var * nly;
        const float vz = t_var * dsz + r_var * nlz;
        const float vmax = fmaxf(fmaxf(vx, vy), vz);

        // voxel coords — exact reference op order (/2 -> *0.5 bit-identical)
        const float cxn = fminf(fmaxf(px / DIVB, -1.0f), 1.0f);
        const float cyn = fminf(fmaxf(py / DIVB, -1.0f), 1.0f);
        const float czn = fminf(fmaxf(pz / DIVB, -1.0f), 1.0f);
        const float cfx = fminf(fmaxf((cxn + 1.0f) * 0.5f * 127.0f, 0.0f), 127.0f);
        const float cfy = fminf(fmaxf((cyn + 1.0f) * 0.5f * 127.0f, 0.0f), 127.0f);
        const float cfz = fminf(fmaxf((czn + 1.0f) * 0.5f * 127.0f, 0.0f), 127.0f);
        const unsigned int ux = (unsigned int)cfx;
        const unsigned int uy = (unsigned int)cfy;
        const unsigned int uz = (unsigned int)cfz;
        unsigned int m = expand_bits(ux) | (expand_bits(uy) << 1) | (expand_bits(uz) << 2);
        if (m > 2097151u) m = 2097151u;
        const int byte = bitfield[m >> 3];          // random gather, L2/L3-resident
        const bool alpha = ((byte >> (int)(m & 7u)) & 1) != 0;
        const bool valid = (!outb) && alpha;

        // dists: z[s+1] from lane+1 (exact bits); lane 63 recomputes with the
        // identical expression from jitter[s+1] (= jloc[k+1] of lane 0).
        // NB: shfls are wave-uniform (outside divergence) — R6's divergent
        // shfl read an inactive lane and corrupted one dist per wave.
        const float jn = (k < 7) ? __shfl(jloc[k + 1], 0) : 0.0f;
        float zn = __shfl_down(z, 1);
        if (lane == 63) zn = 0.2f + STEP * ((float)(s + 1) + jn);
        const float dist = (s < NSAMP - 1) ? (zn - z) : 0.0f;

        floatx4 xw;
        xw[0] = px; xw[1] = py; xw[2] = pz; xw[3] = vmax;
        *reinterpret_cast<floatx4*>(out + (size_t)idx * 4) = xw;
        out[OFF_VALID + idx] = valid ? 1.0f : 0.0f;
        out[OFF_Z + idx]     = z;
        out[OFF_D + idx]     = dist;
    }
}

extern "C" void kernel_launch(void* const* d_in, const int* in_sizes, int n_in,
                              void* d_out, int out_size, void* d_ws, size_t ws_size,
                              hipStream_t stream) {
    const float* rays = (const float*)d_in[0];
    const float* jit  = (const float*)d_in[1];
    const int*   bf   = (const int*)d_in[2];
    float* out = (float*)d_out;

    const int total_threads = NRAYS * NSAMP / 8;   // 1,048,576
    dim3 grid(total_threads / 256), block(256);
    hipLaunchKernelGGL(ca_kernel, grid, block, 0, stream, rays, jit, bf, out);
}

// Round 8
// 49.310 us; speedup vs baseline: 4.4519x; 1.1564x over previous
//
#include <hip/hip_runtime.h>

// Disable FP contraction so every multiply/add rounds exactly like the
// numpy/JAX f32 reference (FMA fusion would change discrete voxel coords
// and flip ray_valid bits, which must be exact).
#pragma clang fp contract(off)

#define NRAYS 16384
#define NSAMP 512

typedef __attribute__((ext_vector_type(4))) float floatx4;

static __device__ __forceinline__ unsigned int expand_bits(unsigned int v) {
    v = (v * 65537u) & 4278190335u;
    v = (v * 257u)   & 251719695u;
    v = (v * 17u)    & 3272356035u;
    v = (v * 5u)     & 1227133513u;
    return v;
}

__global__ __launch_bounds__(256) void ca_kernel(
    const float* __restrict__ rays_chunk,
    const float* __restrict__ jitter,
    const int*   __restrict__ bitfield,
    float* __restrict__ out)
{
#pragma clang fp contract(off)
    const int tid  = blockIdx.x * 256 + threadIdx.x;
    const int ray  = tid >> 6;         // one wave per ray
    const int lane = tid & 63;         // samples s = lane + 64*k, k=0..7

    // Constants: computed in f64 exactly like Python, then cast to f32.
    const float STEP  = (float)((6.0 - 0.2) / 512.0);
    const float HALFS = (float)(((6.0 - 0.2) / 512.0) / 2.0);
    const float C415  = (float)(4.0 / 15.0);
    const float C512  = (float)(5.0 / 12.0);
    const float C13   = (float)(1.0 / 3.0);
    const double br   = 0.0008 * 2.0 / __builtin_sqrt(12.0);
    const float BR2   = (float)(br * br);
    const float DIVB  = 1.984375f;     // BOUND - half_grid, exact in f32

    // Wave-uniform ray params.
    const float* rp = rays_chunk + ray * 6;
    const float ox = rp[0], oy = rp[1], oz = rp[2];
    const float dx = rp[3], dy = rp[4], dz = rp[5];

    // Per-ray null_diag (matches: d_sq, d_mag_sq = max((x+y)+z, 1e-10))
    const float dsx = dx * dx, dsy = dy * dy, dsz = dz * dz;
    float dms = (dsx + dsy) + dsz;
    dms = fmaxf(dms, 1e-10f);
    const float nlx = 1.0f - dsx / dms;
    const float nly = 1.0f - dsy / dms;
    const float nlz = 1.0f - dsz / dms;

    const int sbase = ray * NSAMP;

    // Coalesced jitter loads (256B dense per wave instruction).
    float jloc[8];
#pragma unroll
    for (int k = 0; k < 8; ++k)
        jloc[k] = jitter[sbase + lane + (k << 6)];

    const size_t OFF_VALID = (size_t)NRAYS * NSAMP * 4;             // 33554432
    const size_t OFF_Z     = OFF_VALID + (size_t)NRAYS * NSAMP;     // 41943040
    const size_t OFF_D     = OFF_Z     + (size_t)NRAYS * NSAMP;     // 50331648

#pragma unroll
    for (int k = 0; k < 8; ++k) {
        const int s   = lane + (k << 6);
        const int idx = sbase + s;

        const float z  = 0.2f + STEP * ((float)s + jloc[k]);
        const float t0 = z - HALFS;
        const float t1 = t0 + HALFS;
        const float mu = (t0 + t1) * 0.5f;   // bit-identical to /2
        const float hw = (t1 - t0) * 0.5f;   // bit-identical to /2
        const float mu2 = mu * mu;
        const float hw2 = hw * hw;
        const float hw4 = hw2 * hw2;
        const float denom  = 3.0f * mu2 + hw2;

        // t_mean feeds the discrete voxel cast -> exact IEEE divide kept.
        const float t_mean = mu + ((2.0f * mu) * hw2) / denom;

        // t_var / r_var feed ONLY vmax (|vmax| ~ 1e-5 vs 0.139 abs threshold):
        // approx reciprocal is fine here and removes 3 IEEE divides/sample.
        const float rd     = __builtin_amdgcn_rcpf(denom);
        const float inner  = 12.0f * mu2 - hw2;
        const float t_var  = hw2 * C13 - (C415 * (hw4 * inner)) * (rd * rd);
        const float r_var  = BR2 * ((mu2 * 0.25f + C512 * hw2) - (C415 * hw4) * rd);

        const float px = ox + dx * t_mean;
        const float py = oy + dy * t_mean;
        const float pz = oz + dz * t_mean;

        // |p|>2 == (p<-2)|(p>2) for finite p; abs is a free operand modifier
        const bool outb = (fabsf(px) > 2.0f) | (fabsf(py) > 2.0f) | (fabsf(pz) > 2.0f);

        const float vx = t_var * dsx + r_var * nlx;
        const float vy = t_var * dsy + r_var * nly;
        const float vz = t_var * dsz + r_var * nlz;
        const float vmax = fmaxf(fmaxf(vx, vy), vz);

        // voxel coords — exact reference op order; /DIVB must stay IEEE.
        // Outer clip(.,0,127) dropped: for cxn in [-1,1], (cxn+1)<=2 (RNE),
        // *0.5 exact, *127<=127, >=0 — bit-identical no-op.
        const float cxn = fminf(fmaxf(px / DIVB, -1.0f), 1.0f);
        const float cyn = fminf(fmaxf(py / DIVB, -1.0f), 1.0f);
        const float czn = fminf(fmaxf(pz / DIVB, -1.0f), 1.0f);
        const unsigned int ux = (unsigned int)((cxn + 1.0f) * 0.5f * 127.0f);
        const unsigned int uy = (unsigned int)((cyn + 1.0f) * 0.5f * 127.0f);
        const unsigned int uz = (unsigned int)((czn + 1.0f) * 0.5f * 127.0f);
        // max interleave(127,127,127) == 2097151 == BITS*8-1: clamp is a no-op.
        const unsigned int m =
            expand_bits(ux) | (expand_bits(uy) << 1) | (expand_bits(uz) << 2);
        const int byte = bitfield[m >> 3];          // random gather, L2-resident
        const bool alpha = ((byte >> (int)(m & 7u)) & 1) != 0;
        const bool valid = (!outb) && alpha;

        // dists: z[s+1] from lane+1 (exact bits); lane 63 recomputes with the
        // identical expression from jitter[s+1] (= jloc[k+1] of lane 0).
        // Shfls stay wave-uniform (R6 lesson: divergent shfl = garbage).
        const float jn = (k < 7) ? __shfl(jloc[k + 1], 0) : 0.0f;
        float zn = __shfl_down(z, 1);
        if (lane == 63) zn = 0.2f + STEP * ((float)(s + 1) + jn);
        const float dist = (s < NSAMP - 1) ? (zn - z) : 0.0f;

        floatx4 xw;
        xw[0] = px; xw[1] = py; xw[2] = pz; xw[3] = vmax;
        *reinterpret_cast<floatx4*>(out + (size_t)idx * 4) = xw;
        out[OFF_VALID + idx] = valid ? 1.0f : 0.0f;
        out[OFF_Z + idx]     = z;
        out[OFF_D + idx]     = dist;
    }
}

extern "C" void kernel_launch(void* const* d_in, const int* in_sizes, int n_in,
                              void* d_out, int out_size, void* d_ws, size_t ws_size,
                              hipStream_t stream) {
    const float* rays = (const float*)d_in[0];
    const float* jit  = (const float*)d_in[1];
    const int*   bf   = (const int*)d_in[2];
    float* out = (float*)d_out;

    const int total_threads = NRAYS * NSAMP / 8;   // 1,048,576
    dim3 grid(total_threads / 256), block(256);
    hipLaunchKernelGGL(ca_kernel, grid, block, 0, stream, rays, jit, bf, out);
}

// Round 9
// 48.105 us; speedup vs baseline: 4.5634x; 1.0251x over previous
//
#include <hip/hip_runtime.h>

// Disable FP contraction so every multiply/add rounds exactly like the
// numpy/JAX f32 reference (FMA fusion would change discrete voxel coords
// and flip ray_valid bits, which must be exact). Loose paths (vmax only)
// use explicit __builtin_fmaf.
#pragma clang fp contract(off)

#define NRAYS 16384
#define NSAMP 512

typedef __attribute__((ext_vector_type(4))) float floatx4;

static __device__ __forceinline__ unsigned int expand_bits(unsigned int v) {
    v = (v * 65537u) & 4278190335u;
    v = (v * 257u)   & 251719695u;
    v = (v * 17u)    & 3272356035u;
    v = (v * 5u)     & 1227133513u;
    return v;
}

__global__ __launch_bounds__(256) void ca_kernel(
    const float* __restrict__ rays_chunk,
    const float* __restrict__ jitter,
    const int*   __restrict__ bitfield,
    float* __restrict__ out)
{
#pragma clang fp contract(off)
    const int tid  = blockIdx.x * 256 + threadIdx.x;
    const int ray  = tid >> 6;         // one wave per ray
    const int lane = tid & 63;         // samples s = lane + 64*k, k=0..7

    // Constants: computed in f64 exactly like Python, then cast to f32.
    const float STEP  = (float)((6.0 - 0.2) / 512.0);
    const float HALFS = (float)(((6.0 - 0.2) / 512.0) / 2.0);
    const float C415  = (float)(4.0 / 15.0);
    const float C512  = (float)(5.0 / 12.0);
    const float C13   = (float)(1.0 / 3.0);
    const double br   = 0.0008 * 2.0 / __builtin_sqrt(12.0);
    const float BR2   = (float)(br * br);
    // px/DIVB replaced by f64 multiply with RN64(1/DIVB)=RN64(64/127):
    // bit-identical to IEEE f32 division (halfway-distance >= 2^-36 rel,
    // f64 path error <= 2^-52; exact-quotient case fits in 17 bits).
    const double RCPB = 1.0 / 1.984375;

    // Wave-uniform ray params.
    const float* rp = rays_chunk + ray * 6;
    const float ox = rp[0], oy = rp[1], oz = rp[2];
    const float dx = rp[3], dy = rp[4], dz = rp[5];

    // Per-ray null_diag (matches: d_sq, d_mag_sq = max((x+y)+z, 1e-10))
    const float dsx = dx * dx, dsy = dy * dy, dsz = dz * dz;
    float dms = (dsx + dsy) + dsz;
    dms = fmaxf(dms, 1e-10f);
    const float nlx = 1.0f - dsx / dms;
    const float nly = 1.0f - dsy / dms;
    const float nlz = 1.0f - dsz / dms;

    const int sbase = ray * NSAMP;

    // Coalesced jitter loads (256B dense per wave instruction).
    float jloc[8];
#pragma unroll
    for (int k = 0; k < 8; ++k)
        jloc[k] = jitter[sbase + lane + (k << 6)];

    const size_t OFF_VALID = (size_t)NRAYS * NSAMP * 4;             // 33554432
    const size_t OFF_Z     = OFF_VALID + (size_t)NRAYS * NSAMP;     // 41943040
    const size_t OFF_D     = OFF_Z     + (size_t)NRAYS * NSAMP;     // 50331648

#pragma unroll
    for (int k = 0; k < 8; ++k) {
        const int s   = lane + (k << 6);
        const int idx = sbase + s;

        const float z  = 0.2f + STEP * ((float)s + jloc[k]);
        const float t0 = z - HALFS;
        const float t1 = t0 + HALFS;
        const float mu = (t0 + t1) * 0.5f;   // bit-identical to /2
        const float hw = (t1 - t0) * 0.5f;   // bit-identical to /2
        const float mu2 = mu * mu;
        const float hw2 = hw * hw;
        const float hw4 = hw2 * hw2;
        const float denom  = 3.0f * mu2 + hw2;

        // t_mean feeds the discrete voxel cast -> exact IEEE f32 divide kept.
        const float t_mean = mu + ((2.0f * mu) * hw2) / denom;

        // t_var / r_var feed ONLY vmax (|vmax| ~ 1e-5 vs 0.139 abs threshold):
        // approx reciprocal + fma are fine here.
        const float rd     = __builtin_amdgcn_rcpf(denom);
        const float inner  = 12.0f * mu2 - hw2;
        const float t_var  = __builtin_fmaf(hw2, C13,
                                -((C415 * (hw4 * inner)) * (rd * rd)));
        const float r_var  = BR2 * (__builtin_fmaf(C512, hw2, mu2 * 0.25f)
                                - (C415 * hw4) * rd);

        const float px = ox + dx * t_mean;
        const float py = oy + dy * t_mean;
        const float pz = oz + dz * t_mean;

        // |p|>2 == (p<-2)|(p>2) for finite p; abs is a free operand modifier
        const bool outb = (fabsf(px) > 2.0f) | (fabsf(py) > 2.0f) | (fabsf(pz) > 2.0f);

        const float vx = __builtin_fmaf(t_var, dsx, r_var * nlx);
        const float vy = __builtin_fmaf(t_var, dsy, r_var * nly);
        const float vz = __builtin_fmaf(t_var, dsz, r_var * nlz);
        const float vmax = fmaxf(fmaxf(vx, vy), vz);

        // voxel coords — bit-identical transforms of the reference chain:
        //  * /DIVB -> f64 mul by RN64(64/127)  (proof in header comment)
        //  * (c+1)*0.5*127 -> (c+1)*63.5  (*0.5 exact => same single rounding)
        //  * outer clip(.,0,127) and morton clamp are provable no-ops
        const float cxn = fminf(fmaxf((float)((double)px * RCPB), -1.0f), 1.0f);
        const float cyn = fminf(fmaxf((float)((double)py * RCPB), -1.0f), 1.0f);
        const float czn = fminf(fmaxf((float)((double)pz * RCPB), -1.0f), 1.0f);
        const unsigned int ux = (unsigned int)((cxn + 1.0f) * 63.5f);
        const unsigned int uy = (unsigned int)((cyn + 1.0f) * 63.5f);
        const unsigned int uz = (unsigned int)((czn + 1.0f) * 63.5f);
        const unsigned int m =
            expand_bits(ux) | (expand_bits(uy) << 1) | (expand_bits(uz) << 2);
        const int byte = bitfield[m >> 3];          // random gather, L2-resident
        const bool alpha = ((byte >> (int)(m & 7u)) & 1) != 0;
        const bool valid = (!outb) && alpha;

        // dists: z[s+1] from lane+1 (exact bits); lane 63 recomputes with the
        // identical expression from jitter[s+1] (= jloc[k+1] of lane 0).
        // Shfls stay wave-uniform (R6 lesson: divergent shfl = garbage).
        const float jn = (k < 7) ? __shfl(jloc[k + 1], 0) : 0.0f;
        float zn = __shfl_down(z, 1);
        if (lane == 63) zn = 0.2f + STEP * ((float)(s + 1) + jn);
        const float dist = (s < NSAMP - 1) ? (zn - z) : 0.0f;

        floatx4 xw;
        xw[0] = px; xw[1] = py; xw[2] = pz; xw[3] = vmax;
        *reinterpret_cast<floatx4*>(out + (size_t)idx * 4) = xw;
        out[OFF_VALID + idx] = valid ? 1.0f : 0.0f;
        out[OFF_Z + idx]     = z;
        out[OFF_D + idx]     = dist;
    }
}

extern "C" void kernel_launch(void* const* d_in, const int* in_sizes, int n_in,
                              void* d_out, int out_size, void* d_ws, size_t ws_size,
                              hipStream_t stream) {
    const float* rays = (const float*)d_in[0];
    const float* jit  = (const float*)d_in[1];
    const int*   bf   = (const int*)d_in[2];
    float* out = (float*)d_out;

    const int total_threads = NRAYS * NSAMP / 8;   // 1,048,576
    dim3 grid(total_threads / 256), block(256);
    hipLaunchKernelGGL(ca_kernel, grid, block, 0, stream, rays, jit, bf, out);
}